// Round 1
// baseline (315.582 us; speedup 1.0000x reference)
//
#include <hip/hip_runtime.h>

// DCKModule: conv1(1x1 VALU f32)+BN+ReLU -> conv2(1x1 MFMA) -> 7x7 involution + residual
// B=8 C=256 H=W=96, R=64, G=16 GC=16 K=7 PAD=3
#define Bn   8
#define Cn   256
#define Hn   96
#define Wn   96
#define Rn   64
#define Gn   16
#define GCn  16
#define HWn  (Hn * Wn)          // 9216
#define BN_EPS 1e-5f

#define STRIPS   12             // strips of 8 output rows
#define SROWS    8
#define FMROWS   14             // SROWS + 6 halo rows
#define FMSTRIDE 104            // col idx = fmcol + 3; 96 + 6 halo + 2 pad
#define NCHUNK   6              // six 16-col chunks per strip
#define DFSTRIDE 136            // 128 px + 8 pad
#define GCH      8              // gc per block (gc-split)

typedef short  short8  __attribute__((ext_vector_type(8)));
typedef float  floatx4 __attribute__((ext_vector_type(4)));
typedef float  floatx2 __attribute__((ext_vector_type(2)));

__device__ __forceinline__ unsigned short f2bf(float f) {
    unsigned u = __float_as_uint(f);
    u += 0x7FFFu + ((u >> 16) & 1u);      // round-to-nearest-even
    return (unsigned short)(u >> 16);
}
__device__ __forceinline__ float lo2f(unsigned u) { return __uint_as_float(u << 16); }
__device__ __forceinline__ float hi2f(unsigned u) { return __uint_as_float(u & 0xFFFF0000u); }

// ---------------------------------------------------------------------------
// K0: prep — w2bf (784x64 -> bf16, zero-pad to 816 rows), w1t (BN-folded
// transposed W1: w1t[c][r] = W1[r][c]*iv[r], f32), shift sh[r].
// ---------------------------------------------------------------------------
__global__ __launch_bounds__(256) void k0_prep(
    const float* __restrict__ W1, const float* __restrict__ W2,
    const float* __restrict__ gamma, const float* __restrict__ beta,
    const float* __restrict__ mean,  const float* __restrict__ var,
    unsigned short* __restrict__ w2bf, float* __restrict__ w1t,
    float* __restrict__ shp)
{
    const int i = blockIdx.x * 256 + threadIdx.x;
    if (i < 816 * 64)
        w2bf[i] = (i < 784 * 64) ? f2bf(W2[i]) : (unsigned short)0;
    const int j = i - 816 * 64;
    if (j >= 0 && j < 64 * 256) {
        const int c = j >> 6, r = j & 63;
        const float iv = gamma[r] * rsqrtf(var[r] + BN_EPS);
        w1t[j] = W1[r * 256 + c] * iv;
    }
    const int k = j - 64 * 256;
    if (k >= 0 && k < 64) {
        const float iv = gamma[k] * rsqrtf(var[k] + BN_EPS);
        shp[k] = beta[k] - mean[k] * iv;
    }
}

// ---------------------------------------------------------------------------
// K1: conv1 as register-blocked VALU GEMM (f32 end-to-end, no transpose).
// grid = 8*144 = 1152 blocks x 256. Wave wv owns r in [16*wv, 16*wv+16),
// lane owns one pixel. Per c-step: 1 coalesced guide dword (256 B/wave,
// read once from HBM; 4-wave reuse dedup'd by L1) + 16 FMA against
// wave-uniform BN-folded weights (SGPR-broadcast w1t row). 16 independent
// acc chains give ample FMA ILP; ~4.5 blocks/CU hides latency.
// Floor: max(13.5 us BW, 15.4 us f32-FMA issue) for the whole dispatch.
// ---------------------------------------------------------------------------
__global__ __launch_bounds__(256) void k1_conv1(
    const float* __restrict__ guide, const float* __restrict__ w1t,
    const float* __restrict__ shp, unsigned short* __restrict__ xbf)
{
    const int t    = threadIdx.x;
    const int lane = t & 63;
    const int r0   = __builtin_amdgcn_readfirstlane((t >> 6) << 4);
    const int bx   = blockIdx.x;
    const int b    = bx / 144;
    const int px   = (bx - b * 144) * 64 + lane;

    const float* gp = guide + b * (Cn * HWn) + px;
    const float* wp = w1t + r0;

    float acc[16];
#pragma unroll
    for (int i = 0; i < 16; ++i) acc[i] = 0.f;

#pragma unroll 4
    for (int c = 0; c < Cn; ++c) {
        const float g = gp[c * HWn];
        const float4* wq = (const float4*)(wp + c * 64);
        const float4 w0 = wq[0];
        const float4 w1 = wq[1];
        const float4 w2 = wq[2];
        const float4 w3 = wq[3];
        acc[0]  = fmaf(w0.x, g, acc[0]);
        acc[1]  = fmaf(w0.y, g, acc[1]);
        acc[2]  = fmaf(w0.z, g, acc[2]);
        acc[3]  = fmaf(w0.w, g, acc[3]);
        acc[4]  = fmaf(w1.x, g, acc[4]);
        acc[5]  = fmaf(w1.y, g, acc[5]);
        acc[6]  = fmaf(w1.z, g, acc[6]);
        acc[7]  = fmaf(w1.w, g, acc[7]);
        acc[8]  = fmaf(w2.x, g, acc[8]);
        acc[9]  = fmaf(w2.y, g, acc[9]);
        acc[10] = fmaf(w2.z, g, acc[10]);
        acc[11] = fmaf(w2.w, g, acc[11]);
        acc[12] = fmaf(w3.x, g, acc[12]);
        acc[13] = fmaf(w3.y, g, acc[13]);
        acc[14] = fmaf(w3.z, g, acc[14]);
        acc[15] = fmaf(w3.w, g, acc[15]);
    }

    const float* sp = shp + r0;
    unsigned short* xp = xbf + (unsigned)(b * HWn + px) * 64 + r0;
#pragma unroll
    for (int i = 0; i < 8; ++i) {
        const float v0 = fmaxf(acc[2 * i]     + sp[2 * i],     0.f);
        const float v1 = fmaxf(acc[2 * i + 1] + sp[2 * i + 1], 0.f);
        *(unsigned*)(xp + 2 * i) = (unsigned)f2bf(v0) | ((unsigned)f2bf(v1) << 16);
    }
}

// ---------------------------------------------------------------------------
// K3: fused conv2 (MFMA) + involution + residual. Full-width 8-row strips,
// gc-split: 8 channels per block, twin blocks per (b,strip,g).
// grid = 8*12*16*2 = 3072, 256 threads.
// LDS: sFM 8*14*104*2 = 23,296 + sDF 13,328 = 36,624 B -> 4 blocks/CU.
// ---------------------------------------------------------------------------
__global__ __launch_bounds__(256, 4) void k3_main(
    const float* __restrict__ fm, const unsigned short* __restrict__ xbf,
    const unsigned short* __restrict__ w2bf, float* __restrict__ out)
{
    __shared__ unsigned short sFM[GCH][FMROWS][FMSTRIDE];
    __shared__ unsigned short sDF[49][DFSTRIDE];

    int bx = blockIdx.x;
    const int half  = bx & 1;   bx >>= 1;
    const int g     = bx & 15;  bx >>= 4;
    const int strip = bx % STRIPS;
    const int b     = bx / STRIPS;
    const int row0  = strip * SROWS;
    const int t     = threadIdx.x;
    const int cbase = g * GCn + half * GCH;       // first global channel

    // ---- stage fm strip (8 gc x 14 rows x 96 cols, bf16) ----
    {
        for (int e = t; e < GCH * FMROWS * 8; e += 256) {   // zero halo cols
            const int gc = e / (FMROWS * 8);
            const int rm = e - gc * (FMROWS * 8);
            const int ri = rm >> 3;
            const int z  = rm & 7;
            sFM[gc][ri][(z < 3) ? z : (96 + z)] = 0;
        }
        const float* fb = fm + (b * Cn + cbase) * HWn;
        for (int e = t; e < GCH * FMROWS * 24; e += 256) {
            const int gc = e / (FMROWS * 24);
            const int rm = e - gc * (FMROWS * 24);
            const int ri = rm / 24;
            const int c4 = rm - ri * 24;
            const int gr = row0 + ri - 3;
            float4 v = make_float4(0.f, 0.f, 0.f, 0.f);
            if ((unsigned)gr < (unsigned)Hn)
                v = *(const float4*)(fb + gc * HWn + gr * Wn + c4 * 4);
            sFM[gc][ri][3 + c4 * 4 + 0] = f2bf(v.x);
            sFM[gc][ri][3 + c4 * 4 + 1] = f2bf(v.y);
            sFM[gc][ri][3 + c4 * 4 + 2] = f2bf(v.z);
            sFM[gc][ri][3 + c4 * 4 + 3] = f2bf(v.w);
        }
    }

    const int lane = t & 63, wv = t >> 6;
    const int ln   = lane & 15, quad = lane >> 4;

    // W2 A-frags: held in registers across all chunks (duplicated on twins)
    short8 af[4][2];
    {
        const unsigned short* wb = w2bf + (g * 49 + ln) * 64 + quad * 8;
#pragma unroll
        for (int mt = 0; mt < 4; ++mt) {
            af[mt][0] = *(const short8*)(wb + mt * 16 * 64);
            af[mt][1] = *(const short8*)(wb + mt * 16 * 64 + 32);
        }
    }

    const int r_ = lane >> 3;      // phase-B row 0..7
    const int cp = lane & 7;       // phase-B col-pair 0..7

#pragma unroll 1
    for (int ch = 0; ch < NCHUNK; ++ch) {
        const int cb = ch * 16;

        // ---- phase A: df for this chunk via MFMA ----
#pragma unroll
        for (int jj = 0; jj < 2; ++jj) {
            const int nt = wv * 2 + jj;                 // strip-local row
            const unsigned short* xp =
                xbf + ((b * HWn + (row0 + nt) * Wn + cb + ln) * 64 + quad * 8);
            const short8 b0 = *(const short8*)xp;
            const short8 b1 = *(const short8*)(xp + 32);
            const int px = nt * 16 + ln;
#pragma unroll
            for (int mt = 0; mt < 4; ++mt) {
                floatx4 acc = {0.f, 0.f, 0.f, 0.f};
                acc = __builtin_amdgcn_mfma_f32_16x16x32_bf16(af[mt][0], b0, acc, 0, 0, 0);
                acc = __builtin_amdgcn_mfma_f32_16x16x32_bf16(af[mt][1], b1, acc, 0, 0, 0);
#pragma unroll
                for (int rr = 0; rr < 4; ++rr) {
                    const int m = mt * 16 + quad * 4 + rr;
                    float v = acc[rr];
                    if (m == 24) v += 1.0f;             // residual -> center tap
                    if (m < 49) sDF[m][px] = f2bf(v);
                }
            }
        }
        __syncthreads();

        // ---- phase B: involution for this chunk (2 gc per thread) ----
        {
            float acc[2][2];
#pragma unroll
            for (int gi = 0; gi < 2; ++gi) { acc[gi][0] = 0.f; acc[gi][1] = 0.f; }

#pragma unroll
            for (int di = 0; di < 7; ++di) {
                float dfl[7], dfh[7];
#pragma unroll
                for (int dj = 0; dj < 7; ++dj) {
                    const unsigned u = *(const unsigned*)&sDF[di * 7 + dj][r_ * 16 + 2 * cp];
                    dfl[dj] = lo2f(u); dfh[dj] = hi2f(u);
                }
#pragma unroll
                for (int gi = 0; gi < 2; ++gi) {
                    const int gc = wv * 2 + gi;
                    const unsigned* fp = (const unsigned*)&sFM[gc][r_ + di][cb + 2 * cp];
                    const unsigned u0 = fp[0], u1 = fp[1], u2 = fp[2], u3 = fp[3];
                    const float f[8] = {lo2f(u0), hi2f(u0), lo2f(u1), hi2f(u1),
                                        lo2f(u2), hi2f(u2), lo2f(u3), hi2f(u3)};
#pragma unroll
                    for (int dj = 0; dj < 7; ++dj) {
                        acc[gi][0] = fmaf(f[dj],     dfl[dj], acc[gi][0]);
                        acc[gi][1] = fmaf(f[dj + 1], dfh[dj], acc[gi][1]);
                    }
                }
            }
#pragma unroll
            for (int gi = 0; gi < 2; ++gi) {
                const int gc = wv * 2 + gi;
                floatx2 o2 = {acc[gi][0], acc[gi][1]};
                float* op = out + ((b * Cn + cbase + gc) * Hn + row0 + r_) * Wn
                            + cb + 2 * cp;
                __builtin_nontemporal_store(o2, (floatx2*)op);
            }
        }
        __syncthreads();
    }
}

// ---------------------------------------------------------------------------
extern "C" void kernel_launch(void* const* d_in, const int* in_sizes, int n_in,
                              void* d_out, int out_size, void* d_ws, size_t ws_size,
                              hipStream_t stream)
{
    const float* fm    = (const float*)d_in[0];
    const float* guide = (const float*)d_in[1];
    const float* W1    = (const float*)d_in[2];
    const float* gamma = (const float*)d_in[3];
    const float* beta  = (const float*)d_in[4];
    const float* mean  = (const float*)d_in[5];
    const float* var   = (const float*)d_in[6];
    const float* W2    = (const float*)d_in[7];
    float* out = (float*)d_out;

    // ws: xbf [8][9216][64] u16 (9,437,184 B) | w2bf [816][64] u16 (104,448 B)
    //     | w1t [256][64] f32 (65,536 B) | sh [64] f32 (256 B)
    char* wsb = (char*)d_ws;
    unsigned short* xbf  = (unsigned short*)wsb;
    unsigned short* w2bf = (unsigned short*)(wsb + 9437184);
    float*          w1t  = (float*)(wsb + 9437184 + 104448);
    float*          shp  = (float*)(wsb + 9437184 + 104448 + 65536);

    k0_prep<<<269, 256, 0, stream>>>(W1, W2, gamma, beta, mean, var,
                                     w2bf, w1t, shp);
    k1_conv1<<<Bn * 144, 256, 0, stream>>>(guide, w1t, shp, xbf);
    k3_main<<<Bn * STRIPS * Gn * 2, 256, 0, stream>>>(fm, xbf, w2bf, out);
}

// Round 2
// 277.228 us; speedup vs baseline: 1.1383x; 1.1383x over previous
//
#include <hip/hip_runtime.h>

// DCKModule: conv1(1x1 MFMA)+BN+ReLU -> conv2(1x1 MFMA) -> 7x7 involution + residual
// B=8 C=256 H=W=96, R=64, G=16 GC=16 K=7 PAD=3
#define Bn   8
#define Cn   256
#define Hn   96
#define Wn   96
#define Rn   64
#define Gn   16
#define GCn  16
#define HWn  (Hn * Wn)          // 9216
#define BN_EPS 1e-5f

#define STRIPS   12             // strips of 8 output rows
#define SROWS    8
#define FMROWS   14             // SROWS + 6 halo rows
#define FMCOLS   56             // 48 px + 6 halo + 2 pad (px-split twin)
#define NCHUNK   3              // three 16-col chunks per twin
#define DFSTRIDE 136            // 128 px + 8 pad

typedef short  short8  __attribute__((ext_vector_type(8)));
typedef float  floatx4 __attribute__((ext_vector_type(4)));
typedef float  floatx2 __attribute__((ext_vector_type(2)));

__device__ __forceinline__ unsigned short f2bf(float f) {
    unsigned u = __float_as_uint(f);
    u += 0x7FFFu + ((u >> 16) & 1u);      // round-to-nearest-even
    return (unsigned short)(u >> 16);
}
__device__ __forceinline__ float lo2f(unsigned u) { return __uint_as_float(u << 16); }
__device__ __forceinline__ float hi2f(unsigned u) { return __uint_as_float(u & 0xFFFF0000u); }

// ---------------------------------------------------------------------------
// K0: prep — w2bf (784x64 -> bf16, zero-pad to 816 rows), w1bf (64x256 bf16,
// same layout as W1 = A-operand [m=o][k=c]), folded BN constants iv/sh.
// ---------------------------------------------------------------------------
__global__ __launch_bounds__(256) void k0_prep(
    const float* __restrict__ W1, const float* __restrict__ W2,
    const float* __restrict__ gamma, const float* __restrict__ beta,
    const float* __restrict__ mean,  const float* __restrict__ var,
    unsigned short* __restrict__ w2bf, unsigned short* __restrict__ w1bf,
    float* __restrict__ ivp, float* __restrict__ shp)
{
    const int i = blockIdx.x * 256 + threadIdx.x;
    if (i < 816 * 64)
        w2bf[i] = (i < 784 * 64) ? f2bf(W2[i]) : (unsigned short)0;
    const int j = i - 816 * 64;
    if (j >= 0 && j < 64 * 256)
        w1bf[j] = f2bf(W1[j]);
    const int k = j - 64 * 256;
    if (k >= 0 && k < 64) {
        const float iv = gamma[k] * rsqrtf(var[k] + BN_EPS);
        ivp[k] = iv;
        shp[k] = beta[k] - mean[k] * iv;
    }
}

// ---------------------------------------------------------------------------
// K1: conv1 via MFMA, no LDS, no barriers. x_bf[b][px][64]. (round-0 version)
// ---------------------------------------------------------------------------
__global__ __launch_bounds__(256) void k1_conv1_mfma(
    const float* __restrict__ guide, const unsigned short* __restrict__ w1bf,
    const float* __restrict__ ivp, const float* __restrict__ shp,
    unsigned short* __restrict__ xbf)
{
    const int t    = threadIdx.x;
    const int lane = t & 63, wv = t >> 6;
    const int ln   = lane & 15, quad = lane >> 4;
    const int bx   = blockIdx.x;
    const int b    = bx / 144;
    const int px   = (bx - b * 144) * 64 + wv * 16 + ln;

    const float* gp = guide + b * (Cn * HWn) + (quad * 8) * HWn + px;

    floatx4 acc[4];
#pragma unroll
    for (int mt = 0; mt < 4; ++mt) acc[mt] = (floatx4){0.f, 0.f, 0.f, 0.f};

#pragma unroll 2
    for (int c0 = 0; c0 < Cn; c0 += 32) {
        float bv[8];
#pragma unroll
        for (int j = 0; j < 8; ++j) bv[j] = gp[(c0 + j) * HWn];
        short8 bfrag;
#pragma unroll
        for (int j = 0; j < 8; ++j) bfrag[j] = (short)f2bf(bv[j]);
#pragma unroll
        for (int mt = 0; mt < 4; ++mt) {
            const short8 af = *(const short8*)(w1bf + (mt * 16 + ln) * Cn + c0 + quad * 8);
            acc[mt] = __builtin_amdgcn_mfma_f32_16x16x32_bf16(af, bfrag, acc[mt], 0, 0, 0);
        }
    }

    unsigned short* xp = xbf + (b * HWn + px) * 64;
#pragma unroll
    for (int mt = 0; mt < 4; ++mt) {
#pragma unroll
        for (int rp = 0; rp < 2; ++rp) {
            const int o = mt * 16 + quad * 4 + rp * 2;      // C row
            const float v0 = fmaxf(fmaf(acc[mt][rp * 2],     ivp[o],     shp[o]),     0.f);
            const float v1 = fmaxf(fmaf(acc[mt][rp * 2 + 1], ivp[o + 1], shp[o + 1]), 0.f);
            *(unsigned*)(xp + o) = (unsigned)f2bf(v0) | ((unsigned)f2bf(v1) << 16);
        }
    }
}

// ---------------------------------------------------------------------------
// K3: fused conv2 (MFMA) + involution + residual.
// PX-SPLIT twins: each block owns ALL 16 gc but only 48 output cols
// (half*48..+47), so df is computed exactly once per pixel (phase A and the
// xbf fetch are halved vs the gc-split design), 3 chunks -> 6 barriers.
// grid = 8*12*16*2 = 3072, 256 threads.
// LDS: sFM 16*14*56*2 = 25,088 + sDF 13,328 = 38,416 B -> 4 blocks/CU.
// Phase B accumulates px-pairs in floatx2 -> v_pk_fma_f32 (full-rate f32).
// ---------------------------------------------------------------------------
__global__ __launch_bounds__(256, 4) void k3_main(
    const float* __restrict__ fm, const unsigned short* __restrict__ xbf,
    const unsigned short* __restrict__ w2bf, float* __restrict__ out)
{
    __shared__ unsigned short sFM[GCn][FMROWS][FMCOLS];
    __shared__ unsigned short sDF[49][DFSTRIDE];

    int bx = blockIdx.x;
    const int half  = bx & 1;   bx >>= 1;
    const int g     = bx & 15;  bx >>= 4;
    const int strip = bx % STRIPS;
    const int b     = bx / STRIPS;
    const int row0  = strip * SROWS;
    const int t     = threadIdx.x;
    const int c0    = half * 48;                  // first output col of twin

    // ---- stage fm strip: 16 gc x 14 rows x (48 px + 6 halo) cols, bf16 ----
    // array col L = global_col - c0 + 3; quads at L = 4q-1 (q=0..13) cover
    // L -1..54; OOB rows/cols write zeros (no separate zero pass).
    {
        const float* fb = fm + (b * Cn + g * GCn) * HWn;
        for (int e = t; e < GCn * FMROWS * 14; e += 256) {
            const int q  = e % 14;
            const int rm = e / 14;
            const int ri = rm % FMROWS;
            const int gc = rm / FMROWS;
            const int gr   = row0 + ri - 3;
            const int gcol = c0 - 4 + q * 4;
            float4 v = make_float4(0.f, 0.f, 0.f, 0.f);
            if ((unsigned)gr < (unsigned)Hn && (unsigned)gcol < (unsigned)Wn)
                v = *(const float4*)(fb + gc * HWn + gr * Wn + gcol);
            const int L = q * 4 - 1;
            if (L >= 0)  sFM[gc][ri][L]     = f2bf(v.x);
            if (L + 1 <= 54) sFM[gc][ri][L + 1] = f2bf(v.y);
            if (L + 2 <= 54) sFM[gc][ri][L + 2] = f2bf(v.z);
            if (L + 3 <= 54) sFM[gc][ri][L + 3] = f2bf(v.w);
        }
    }

    const int lane = t & 63, wv = t >> 6;
    const int ln   = lane & 15, quad = lane >> 4;

    // W2 A-frags: held in registers across all chunks
    short8 af[4][2];
    {
        const unsigned short* wb = w2bf + (g * 49 + ln) * 64 + quad * 8;
#pragma unroll
        for (int mt = 0; mt < 4; ++mt) {
            af[mt][0] = *(const short8*)(wb + mt * 16 * 64);
            af[mt][1] = *(const short8*)(wb + mt * 16 * 64 + 32);
        }
    }

    const int r_ = lane >> 3;      // phase-B row 0..7
    const int cp = lane & 7;       // phase-B col-pair 0..7

#pragma unroll 1
    for (int ch = 0; ch < NCHUNK; ++ch) {
        const int cb = ch * 16;

        // ---- phase A: df for this chunk via MFMA (each px computed once) ----
#pragma unroll
        for (int jj = 0; jj < 2; ++jj) {
            const int nt = wv * 2 + jj;                 // strip-local row
            const unsigned short* xp =
                xbf + ((b * HWn + (row0 + nt) * Wn + c0 + cb + ln) * 64 + quad * 8);
            const short8 b0 = *(const short8*)xp;
            const short8 b1 = *(const short8*)(xp + 32);
            const int px = nt * 16 + ln;
#pragma unroll
            for (int mt = 0; mt < 4; ++mt) {
                floatx4 acc = {0.f, 0.f, 0.f, 0.f};
                acc = __builtin_amdgcn_mfma_f32_16x16x32_bf16(af[mt][0], b0, acc, 0, 0, 0);
                acc = __builtin_amdgcn_mfma_f32_16x16x32_bf16(af[mt][1], b1, acc, 0, 0, 0);
#pragma unroll
                for (int rr = 0; rr < 4; ++rr) {
                    const int m = mt * 16 + quad * 4 + rr;
                    float v = acc[rr];
                    if (m == 24) v += 1.0f;             // residual -> center tap
                    if (m < 49) sDF[m][px] = f2bf(v);
                }
            }
        }
        __syncthreads();

        // ---- phase B: involution for this chunk (4 gc x px-pair / thread) ----
        {
            floatx2 acc2[4];
#pragma unroll
            for (int gi = 0; gi < 4; ++gi) acc2[gi] = (floatx2){0.f, 0.f};

#pragma unroll
            for (int di = 0; di < 7; ++di) {
                floatx2 dfv[7];
#pragma unroll
                for (int dj = 0; dj < 7; ++dj) {
                    const unsigned u = *(const unsigned*)&sDF[di * 7 + dj][r_ * 16 + 2 * cp];
                    dfv[dj] = (floatx2){lo2f(u), hi2f(u)};
                }
#pragma unroll
                for (int gi = 0; gi < 4; ++gi) {
                    const int gc = wv * 4 + gi;
                    const unsigned* fp = (const unsigned*)&sFM[gc][r_ + di][cb + 2 * cp];
                    const unsigned u0 = fp[0], u1 = fp[1], u2 = fp[2], u3 = fp[3];
                    const float f[8] = {lo2f(u0), hi2f(u0), lo2f(u1), hi2f(u1),
                                        lo2f(u2), hi2f(u2), lo2f(u3), hi2f(u3)};
#pragma unroll
                    for (int dj = 0; dj < 7; ++dj) {
                        const floatx2 fv = (floatx2){f[dj], f[dj + 1]};
                        acc2[gi] += fv * dfv[dj];       // -> v_pk_fma_f32
                    }
                }
            }
#pragma unroll
            for (int gi = 0; gi < 4; ++gi) {
                const int gc = wv * 4 + gi;
                float* op = out + ((b * Cn + g * GCn + gc) * Hn + row0 + r_) * Wn
                            + c0 + cb + 2 * cp;
                __builtin_nontemporal_store(acc2[gi], (floatx2*)op);
            }
        }
        __syncthreads();
    }
}

// ---------------------------------------------------------------------------
extern "C" void kernel_launch(void* const* d_in, const int* in_sizes, int n_in,
                              void* d_out, int out_size, void* d_ws, size_t ws_size,
                              hipStream_t stream)
{
    const float* fm    = (const float*)d_in[0];
    const float* guide = (const float*)d_in[1];
    const float* W1    = (const float*)d_in[2];
    const float* gamma = (const float*)d_in[3];
    const float* beta  = (const float*)d_in[4];
    const float* mean  = (const float*)d_in[5];
    const float* var   = (const float*)d_in[6];
    const float* W2    = (const float*)d_in[7];
    float* out = (float*)d_out;

    // ws: xbf [8][9216][64] u16 (9,437,184 B) | w2bf [816][64] u16 (104,448 B)
    //     | w1bf [64][256] u16 (32,768 B) | iv [64] f32 | sh [64] f32
    char* wsb = (char*)d_ws;
    unsigned short* xbf  = (unsigned short*)wsb;
    unsigned short* w2bf = (unsigned short*)(wsb + 9437184);
    unsigned short* w1bf = (unsigned short*)(wsb + 9437184 + 104448);
    float*          ivp  = (float*)(wsb + 9437184 + 104448 + 32768);
    float*          shp  = ivp + 64;

    k0_prep<<<269, 256, 0, stream>>>(W1, W2, gamma, beta, mean, var,
                                     w2bf, w1bf, ivp, shp);
    k1_conv1_mfma<<<Bn * 144, 256, 0, stream>>>(guide, w1bf, ivp, shp, xbf);
    k3_main<<<Bn * STRIPS * Gn * 2, 256, 0, stream>>>(fm, xbf, w2bf, out);
}